// Round 12
// baseline (34.590 us; speedup 1.0000x reference)
//
#include <hip/hip_runtime.h>

#define BB 2
#define CC 64
#define CI 32
#define NPIX 9216          // 96*96
#define CH 128             // pixels per chunk/block
#define NCHK (NPIX / CH)   // 72 chunks per batch
#define NB (BB * NCHK)     // 144 blocks
#define SLOT (CI * CI)     // 1024 floats per M-partial slot

// ---------------------------------------------------------------------------
// k1: per-(batch,chunk) partial M_c = (pw Xc + pb 1^T)(gw Xc + gb 1^T)^T
//     -> distinct slot. 512 threads; LDS-heavy phases use fat register tiles.
// ---------------------------------------------------------------------------
__global__ __launch_bounds__(512) void k1_Mpart(
    const float* __restrict__ x, const float* __restrict__ pw,
    const float* __restrict__ pb, const float* __restrict__ gw,
    const float* __restrict__ gb, float* __restrict__ Mpart) {
  __shared__ float xt[CC][CH + 4];       // [64][132] 33.8 KB
  __shared__ float pgw[2 * CI][CC + 4];  // [64][68]  17.4 KB
  __shared__ float Ps[CI][CH + 4];       // [32][132] 16.9 KB
  __shared__ float Gs[CI][CH + 4];       //           16.9 KB
  const int t = threadIdx.x;
  const int blk = blockIdx.x;
  const int batch = blk / NCHK;
  const int chk = blk - batch * NCHK;
  const float* __restrict__ X = x + (size_t)batch * CC * NPIX + chk * CH;

  // stage X chunk (64ch x 128px): 2048 float4, 4/thread, coalesced
#pragma unroll
  for (int h = 0; h < 4; ++h) {
    const int idx = t + 512 * h;
    const int c = idx >> 5;
    const int p4 = (idx & 31) * 4;
    *reinterpret_cast<float4*>(&xt[c][p4]) =
        *reinterpret_cast<const float4*>(&X[(size_t)c * NPIX + p4]);
  }
  // stage pw+gw rows (row r<32: pw, r>=32: gw), 1024 float4, 2/thread
#pragma unroll
  for (int h = 0; h < 2; ++h) {
    const int idx = t + 512 * h;
    const int r = idx >> 4;
    const int c4 = (idx & 15) * 4;
    const float* src = (r < CI) ? &pw[r * CC + c4] : &gw[(r - CI) * CC + c4];
    *reinterpret_cast<float4*>(&pgw[r][c4]) =
        *reinterpret_cast<const float4*>(src);
  }
  __syncthreads();

  // P' = pw X + pb, G' = gw X + gb : 128 threads, tile = 4k x 8px (P and G)
  if (t < 128) {
    const int k0 = (t >> 4) * 4;   // 4 consecutive k rows
    const int p0 = (t & 15) * 8;   // 8-px strip
    float pa[4][8] = {};
    float ga[4][8] = {};
    for (int c4 = 0; c4 < CC; c4 += 4) {
      float4 wp[4], wg[4];
#pragma unroll
      for (int i = 0; i < 4; ++i) {
        wp[i] = *reinterpret_cast<const float4*>(&pgw[k0 + i][c4]);
        wg[i] = *reinterpret_cast<const float4*>(&pgw[CI + k0 + i][c4]);
      }
#pragma unroll
      for (int j = 0; j < 4; ++j) {
        const float4 xa = *reinterpret_cast<const float4*>(&xt[c4 + j][p0]);
        const float4 xb =
            *reinterpret_cast<const float4*>(&xt[c4 + j][p0 + 4]);
        const float xv[8] = {xa.x, xa.y, xa.z, xa.w, xb.x, xb.y, xb.z, xb.w};
#pragma unroll
        for (int i = 0; i < 4; ++i) {
          const float wpv = (&wp[i].x)[j];
          const float wgv = (&wg[i].x)[j];
#pragma unroll
          for (int p = 0; p < 8; ++p) {
            pa[i][p] += wpv * xv[p];
            ga[i][p] += wgv * xv[p];
          }
        }
      }
    }
#pragma unroll
    for (int i = 0; i < 4; ++i) {
      const float pbk = pb[k0 + i];
      const float gbk = gb[k0 + i];
      *reinterpret_cast<float4*>(&Ps[k0 + i][p0]) = make_float4(
          pa[i][0] + pbk, pa[i][1] + pbk, pa[i][2] + pbk, pa[i][3] + pbk);
      *reinterpret_cast<float4*>(&Ps[k0 + i][p0 + 4]) = make_float4(
          pa[i][4] + pbk, pa[i][5] + pbk, pa[i][6] + pbk, pa[i][7] + pbk);
      *reinterpret_cast<float4*>(&Gs[k0 + i][p0]) = make_float4(
          ga[i][0] + gbk, ga[i][1] + gbk, ga[i][2] + gbk, ga[i][3] + gbk);
      *reinterpret_cast<float4*>(&Gs[k0 + i][p0 + 4]) = make_float4(
          ga[i][4] + gbk, ga[i][5] + gbk, ga[i][6] + gbk, ga[i][7] + gbk);
    }
  }
  __syncthreads();

  // M_c = P' G'^T : 256 threads, tile = 2kk x 2l, full K=128
  if (t < 256) {
    const int kk0 = (t >> 4) * 2;
    const int l0 = (t & 15) * 2;
    float m[2][2] = {};
    for (int p4 = 0; p4 < CH; p4 += 4) {
      const float4 pv0 = *reinterpret_cast<const float4*>(&Ps[kk0][p4]);
      const float4 pv1 = *reinterpret_cast<const float4*>(&Ps[kk0 + 1][p4]);
      const float4 g0 = *reinterpret_cast<const float4*>(&Gs[l0][p4]);
      const float4 g1 = *reinterpret_cast<const float4*>(&Gs[l0 + 1][p4]);
      m[0][0] += pv0.x * g0.x + pv0.y * g0.y + pv0.z * g0.z + pv0.w * g0.w;
      m[0][1] += pv0.x * g1.x + pv0.y * g1.y + pv0.z * g1.z + pv0.w * g1.w;
      m[1][0] += pv1.x * g0.x + pv1.y * g0.y + pv1.z * g0.z + pv1.w * g0.w;
      m[1][1] += pv1.x * g1.x + pv1.y * g1.y + pv1.z * g1.z + pv1.w * g1.w;
    }
    float* Mp = Mpart + (size_t)blk * SLOT;
    *reinterpret_cast<float2*>(&Mp[kk0 * CI + l0]) = make_float2(m[0][0], m[0][1]);
    *reinterpret_cast<float2*>(&Mp[(kk0 + 1) * CI + l0]) =
        make_float2(m[1][0], m[1][1]);
  }
}

// ---------------------------------------------------------------------------
// k2: reduce 72 M-partials -> M, algebra (fat-tile, tw/rw from L2),
//     apply Z = X + W X + b. 512 threads.
// ---------------------------------------------------------------------------
__global__ __launch_bounds__(512) void k2_apply(
    const float* __restrict__ x, const float* __restrict__ tw,
    const float* __restrict__ tb, const float* __restrict__ rw,
    const float* __restrict__ rb, const float* __restrict__ Mpart,
    float* __restrict__ z) {
  __shared__ float xt[CC][CH + 4];   // [64][132] 33.8 KB
  __shared__ float Wt[CC][CC + 4];   // [64][68]  17.4 KB  Wt[in_j][out_o]
  __shared__ float T1[CI][CC + 4];   // [32][68]   8.7 KB
  __shared__ float Ms[CI][CI + 4];   // [32][36]   4.6 KB
  __shared__ float t2[CI];
  __shared__ float bl[CC];
  const int t = threadIdx.x;
  const int blk = blockIdx.x;
  const int batch = blk / NCHK;
  const int chk = blk - batch * NCHK;

  // stage x tile (2048 float4, 4/thread)
#pragma unroll
  for (int h = 0; h < 4; ++h) {
    const int idx = t + 512 * h;
    const int c = idx >> 5;
    const int p4 = (idx & 31) * 4;
    *reinterpret_cast<float4*>(&xt[c][p4]) = *reinterpret_cast<const float4*>(
        &x[(size_t)batch * CC * NPIX + (size_t)c * NPIX + chk * CH + p4]);
  }

  // M-reduce: thread t owns elements t and t+512; 72 coalesced loads each
  {
    const float* __restrict__ Mp = Mpart + (size_t)batch * NCHK * SLOT;
    float s0 = 0.f, s1 = 0.f;
#pragma unroll 8
    for (int k = 0; k < NCHK; ++k) {
      s0 += Mp[(size_t)k * SLOT + t];
      s1 += Mp[(size_t)k * SLOT + t + 512];
    }
    Ms[t >> 5][t & 31] = s0;
    Ms[(t + 512) >> 5][(t + 512) & 31] = s1;
  }
  __syncthreads();

  // T1[c][j] = sum_k Ms[k][c] tw[k][j] : 64 threads, tile = 4c x 8j
  if (t < 64) {
    const int c0 = (t >> 3) * 4;
    const int jo = (t & 7) * 8;
    float a[4][8] = {};
    for (int k = 0; k < CI; ++k) {
      const float4 mv = *reinterpret_cast<const float4*>(&Ms[k][c0]);
      const float4 w0 = *reinterpret_cast<const float4*>(&tw[k * CC + jo]);
      const float4 w1 = *reinterpret_cast<const float4*>(&tw[k * CC + jo + 4]);
      const float wv[8] = {w0.x, w0.y, w0.z, w0.w, w1.x, w1.y, w1.z, w1.w};
      const float mva[4] = {mv.x, mv.y, mv.z, mv.w};
#pragma unroll
      for (int ci = 0; ci < 4; ++ci)
#pragma unroll
        for (int j = 0; j < 8; ++j) a[ci][j] += mva[ci] * wv[j];
    }
#pragma unroll
    for (int ci = 0; ci < 4; ++ci) {
      *reinterpret_cast<float4*>(&T1[c0 + ci][jo]) =
          make_float4(a[ci][0], a[ci][1], a[ci][2], a[ci][3]);
      *reinterpret_cast<float4*>(&T1[c0 + ci][jo + 4]) =
          make_float4(a[ci][4], a[ci][5], a[ci][6], a[ci][7]);
    }
  } else if (t < 96) {
    // t2[c] = sum_k Ms[k][c] tb[k]
    const int c = t - 64;
    float s = 0.f;
    for (int k = 0; k < CI; ++k) s += Ms[k][c] * tb[k];
    t2[c] = s;
  }
  __syncthreads();

  // Wt[j][o] = invN * sum_c rw[o][c] T1[c][j] : 64 threads, tile = 8o x 8j
  if (t < 64) {
    const int og = (t >> 3) * 8;
    const int jo = (t & 7) * 8;
    float a[8][8] = {};
    for (int c4 = 0; c4 < CI; c4 += 4) {
      float4 rv[8];
#pragma unroll
      for (int oi = 0; oi < 8; ++oi)
        rv[oi] = *reinterpret_cast<const float4*>(&rw[(og + oi) * CI + c4]);
#pragma unroll
      for (int cj = 0; cj < 4; ++cj) {
        const float4 t0 = *reinterpret_cast<const float4*>(&T1[c4 + cj][jo]);
        const float4 t1 =
            *reinterpret_cast<const float4*>(&T1[c4 + cj][jo + 4]);
        const float tv[8] = {t0.x, t0.y, t0.z, t0.w, t1.x, t1.y, t1.z, t1.w};
#pragma unroll
        for (int oi = 0; oi < 8; ++oi) {
          const float rvv = (&rv[oi].x)[cj];
#pragma unroll
          for (int j = 0; j < 8; ++j) a[oi][j] += rvv * tv[j];
        }
      }
    }
    const float invN = 1.0f / (float)NPIX;
#pragma unroll
    for (int j = 0; j < 8; ++j) {
      *reinterpret_cast<float4*>(&Wt[jo + j][og]) =
          make_float4(a[0][j] * invN, a[1][j] * invN, a[2][j] * invN,
                      a[3][j] * invN);
      *reinterpret_cast<float4*>(&Wt[jo + j][og + 4]) =
          make_float4(a[4][j] * invN, a[5][j] * invN, a[6][j] * invN,
                      a[7][j] * invN);
    }
  } else if (t < 128) {
    // bl[o] = invN * sum_c rw[o][c] t2[c] + rb[o]
    const int o = t - 64;
    float s = 0.f;
    for (int c = 0; c < CI; ++c) s += rw[o * CI + c] * t2[c];
    bl[o] = s * (1.0f / (float)NPIX) + rb[o];
  }
  __syncthreads();

  // apply: Z = X + W X + b : 128 threads, tile = 8oc x 8px
  if (t < 128) {
    const int c0 = (t >> 4) * 8;
    const int p0 = (t & 15) * 8;
    const int n0 = chk * CH;
    float* __restrict__ Z = z + (size_t)batch * CC * NPIX;
    float acc[8][8] = {};
    for (int k = 0; k < CC; ++k) {
      const float4 xa = *reinterpret_cast<const float4*>(&xt[k][p0]);
      const float4 xb = *reinterpret_cast<const float4*>(&xt[k][p0 + 4]);
      const float4 w0 = *reinterpret_cast<const float4*>(&Wt[k][c0]);
      const float4 w1 = *reinterpret_cast<const float4*>(&Wt[k][c0 + 4]);
      const float xv[8] = {xa.x, xa.y, xa.z, xa.w, xb.x, xb.y, xb.z, xb.w};
      const float wv[8] = {w0.x, w0.y, w0.z, w0.w, w1.x, w1.y, w1.z, w1.w};
#pragma unroll
      for (int oi = 0; oi < 8; ++oi)
#pragma unroll
        for (int p = 0; p < 8; ++p) acc[oi][p] += wv[oi] * xv[p];
    }
#pragma unroll
    for (int oi = 0; oi < 8; ++oi) {
      const int c = c0 + oi;
      const float bb2 = bl[c];
      const float4 xa = *reinterpret_cast<const float4*>(&xt[c][p0]);
      const float4 xb = *reinterpret_cast<const float4*>(&xt[c][p0 + 4]);
      *reinterpret_cast<float4*>(&Z[(size_t)c * NPIX + n0 + p0]) =
          make_float4(acc[oi][0] + xa.x + bb2, acc[oi][1] + xa.y + bb2,
                      acc[oi][2] + xa.z + bb2, acc[oi][3] + xa.w + bb2);
      *reinterpret_cast<float4*>(&Z[(size_t)c * NPIX + n0 + p0 + 4]) =
          make_float4(acc[oi][4] + xb.x + bb2, acc[oi][5] + xb.y + bb2,
                      acc[oi][6] + xb.z + bb2, acc[oi][7] + xb.w + bb2);
    }
  }
}

extern "C" void kernel_launch(void* const* d_in, const int* in_sizes, int n_in,
                              void* d_out, int out_size, void* d_ws,
                              size_t ws_size, hipStream_t stream) {
  (void)in_sizes; (void)n_in; (void)out_size; (void)ws_size;
  const float* x  = (const float*)d_in[0];
  const float* tw = (const float*)d_in[1];
  const float* tb = (const float*)d_in[2];
  const float* pw = (const float*)d_in[3];
  const float* pb = (const float*)d_in[4];
  const float* gw = (const float*)d_in[5];
  const float* gb = (const float*)d_in[6];
  const float* rw = (const float*)d_in[7];
  const float* rb = (const float*)d_in[8];
  float* z = (float*)d_out;

  float* Mpart = (float*)d_ws;  // NB * 1024 floats = 589 KB

  hipLaunchKernelGGL(k1_Mpart, dim3(NB), dim3(512), 0, stream,
                     x, pw, pb, gw, gb, Mpart);
  hipLaunchKernelGGL(k2_apply, dim3(NB), dim3(512), 0, stream,
                     x, tw, tb, rw, rb, Mpart, z);
}